// Round 3
// baseline (459.979 us; speedup 1.0000x reference)
//
#include <hip/hip_runtime.h>
#include <hip/hip_bf16.h>

typedef __bf16 bf16_t;
typedef __bf16 bf16x8 __attribute__((ext_vector_type(8)));
typedef __bf16 bf16x4 __attribute__((ext_vector_type(4)));
typedef float f32x16 __attribute__((ext_vector_type(16)));

#define QS   256.0f
#define QINV 0.00390625f

__device__ __forceinline__ void async_copy16(const bf16_t* g, bf16_t* l) {
  __builtin_amdgcn_global_load_lds(
      (__attribute__((address_space(1))) void*)g,
      (__attribute__((address_space(3))) void*)l,
      16, 0, 0);
}

// C = quantize-epilogue(A @ Bt^T + bias)
// A:  [M][K] bf16 row-major; Bt: [N][K] bf16 row-major (B transposed)
// 32x32x16 MFMA, each wave computes 64x64 as 2x2 tiles of 32x32.
// LDS XOR swizzle: 16B chunk c of row r stored at phys chunk c ^ (r & 7)
// (staging side permutes which GLOBAL chunk each lane fetches, since
// global_load_lds pins LDS slot = wave base + lane*16).
// XSWZ: remap blocks so all gridDim.x N-blocks of one M-row land on one XCD
// (requires gridDim.x == 8, gridDim.y == 128).
template <bool GELU, typename OutT, bool XSWZ>
__global__ __launch_bounds__(256, 4)
void gemm_tile(const bf16_t* __restrict__ A, const bf16_t* __restrict__ Bt,
               const float* __restrict__ bias, OutT* __restrict__ C,
               int M, int N, int K) {
  __shared__ __attribute__((aligned(16))) bf16_t As[128 * 64];
  __shared__ __attribute__((aligned(16))) bf16_t Bs[128 * 64];
  __shared__ float Yt[33];

  const int tid = threadIdx.x;
  const int lane = tid & 63;
  const int wv = tid >> 6;
  const int wy = wv >> 1;    // wave row (0/1) -> 64 rows
  const int wx = wv & 1;     // wave col (0/1) -> 64 cols
  const int l31 = lane & 31;
  const int hh = lane >> 5;  // half-wave 0/1

  if (GELU && tid < 33) {
    float xv = -4.0f + 0.25f * (float)tid;
    Yt[tid] = 0.5f * xv * (1.0f + erff(xv * 0.70710678f));
  }

  int bx = blockIdx.x, by = blockIdx.y;
  if (XSWZ) {
    // flat dispatch id, x fastest; XCD = flat & 7 on 8-XCD MI355X.
    const int f = by * 8 + bx;
    const int xcd = f & 7;
    const int s = f >> 3;
    bx = s & 7;
    by = xcd * 16 + (s >> 3);  // XCD k owns M-rows [16k, 16k+16)
  }

  const int mBase = by * 128;
  const int nBase = bx * 128;

  const bf16_t* aTile = A + (size_t)mBase * K;
  const bf16_t* bTile = Bt + (size_t)nBase * K;

  f32x16 acc[2][2];
#pragma unroll
  for (int i = 0; i < 2; ++i)
#pragma unroll
    for (int j = 0; j < 2; ++j)
      acc[i][j] = (f32x16){0.f};

  const int srow = tid >> 3;                              // 0..31 (row within 32-row pass)
  const int scb = (((tid & 7) ^ ((tid >> 3) & 7)) * 8);   // swizzled global chunk for this lane

  const int swz_r = l31 & 7;  // read-side row swizzle key

  for (int k0 = 0; k0 < K; k0 += 64) {
    // ---- stage A,B tiles (128 x 64 bf16 each) via async global->LDS, 16B/lane
#pragma unroll
    for (int p = 0; p < 4; ++p) {
      const int row = p * 32 + srow;
      const size_t go = (size_t)row * K + k0 + scb;
      const int lo = (p * 256 + wv * 64) * 8;  // wave-uniform segment base (elements)
      async_copy16(aTile + go, As + lo);
      async_copy16(bTile + go, Bs + lo);
    }
    __syncthreads();  // drains vmcnt: tiles resident

    // ---- compute: 4 k-substeps of 16; 4 ds_read_b128 + 4 MFMA-32x32 each
#pragma unroll
    for (int ks = 0; ks < 4; ++ks) {
      // A-frag: A[m=l31][k = hh*8 + j]; phys chunk = (ks*2+hh) ^ (row&7)
      const int chunk = ((ks * 2 + hh) ^ swz_r) * 8;
      bf16x8 af[2], bfr[2];
#pragma unroll
      for (int i = 0; i < 2; ++i) {
        af[i]  = *(const bf16x8*)(As + (wy * 64 + i * 32 + l31) * 64 + chunk);
        bfr[i] = *(const bf16x8*)(Bs + (wx * 64 + i * 32 + l31) * 64 + chunk);
      }
#pragma unroll
      for (int i = 0; i < 2; ++i)
#pragma unroll
        for (int j = 0; j < 2; ++j)
          acc[i][j] = __builtin_amdgcn_mfma_f32_32x32x16_bf16(af[i], bfr[j], acc[i][j], 0, 0, 0);
    }
    __syncthreads();  // all waves done reading before next stage
  }

  // ---- epilogue: bias + quantize (+ PWL GELU)
  // C/D layout (m74/m101): col = lane&31, row = (reg&3) + 8*(reg>>2) + 4*(lane>>5)
  float bj[2];
#pragma unroll
  for (int j = 0; j < 2; ++j)
    bj[j] = bias[nBase + wx * 64 + j * 32 + l31];

#pragma unroll
  for (int i = 0; i < 2; ++i) {
#pragma unroll
    for (int j = 0; j < 2; ++j) {
      const int cn = nBase + wx * 64 + j * 32 + l31;
#pragma unroll
      for (int reg = 0; reg < 16; ++reg) {
        const int rm = mBase + wy * 64 + i * 32 + (reg & 3) + 8 * (reg >> 2) + 4 * hh;
        float c = acc[i][j][reg] + bj[j];
        float v;
        if (GELU) {
          float xq = rintf(c * QS) * QINV;           // float2fix (Positional_0)
          if (xq > 4.0f) {
            v = xq;
          } else if (xq < -4.0f) {
            v = 0.0f;
          } else {
            float t = (xq + 4.0f) * 4.0f;            // exact: /0.25
            int ii = (int)t;
            ii = ii > 31 ? 31 : ii;
            float f = t - (float)ii;
            float y0 = Yt[ii];
            v = fmaf(f, Yt[ii + 1] - y0, y0);
          }
          v = rintf(v * QS) * QINV;                  // quantize out (+Positional_1 idempotent)
        } else {
          v = rintf(c * QS) * QINV;                  // Positional_2
        }
        C[(size_t)rm * N + cn] = (OutT)v;
      }
    }
  }
}

__global__ void cvt_bf16_kernel(const float* __restrict__ in, bf16_t* __restrict__ out, int n4) {
  int idx = blockIdx.x * blockDim.x + threadIdx.x;
  if (idx < n4) {
    const float4 v = ((const float4*)in)[idx];
    bf16x4 o;
    o[0] = (bf16_t)v.x; o[1] = (bf16_t)v.y; o[2] = (bf16_t)v.z; o[3] = (bf16_t)v.w;
    ((bf16x4*)out)[idx] = o;
  }
}

// in: [R][C] f32 row-major -> out: [C][R] bf16 row-major
__global__ void transpose_cvt_kernel(const float* __restrict__ in, bf16_t* __restrict__ out,
                                     int R, int C) {
  __shared__ float t[32][33];
  const int c0 = blockIdx.x * 32;
  const int r0 = blockIdx.y * 32;
  const int tx = threadIdx.x;
  const int ty = threadIdx.y;  // 0..7
#pragma unroll
  for (int dy = 0; dy < 32; dy += 8)
    t[ty + dy][tx] = in[(size_t)(r0 + ty + dy) * C + c0 + tx];
  __syncthreads();
#pragma unroll
  for (int dy = 0; dy < 32; dy += 8)
    out[(size_t)(c0 + ty + dy) * R + r0 + tx] = (bf16_t)t[tx][ty + dy];
}

extern "C" void kernel_launch(void* const* d_in, const int* in_sizes, int n_in,
                              void* d_out, int out_size, void* d_ws, size_t ws_size,
                              hipStream_t stream) {
  const float* x  = (const float*)d_in[0];   // [32,512,1024] = [16384][1024]
  const float* w1 = (const float*)d_in[1];   // [1024][4096]
  const float* b1 = (const float*)d_in[2];   // [4096]
  const float* w2 = (const float*)d_in[3];   // [4096][1024]
  const float* b2 = (const float*)d_in[4];   // [1024]
  float* out = (float*)d_out;                // [16384][1024]

  const int M = 16384, D = 1024, F = 4096;

  char* ws = (char*)d_ws;
  size_t off = 0;
  bf16_t* xb  = (bf16_t*)(ws + off); off += (size_t)M * D * 2;  // 33.5 MB
  bf16_t* w1t = (bf16_t*)(ws + off); off += (size_t)D * F * 2;  //  8.4 MB
  bf16_t* w2t = (bf16_t*)(ws + off); off += (size_t)F * D * 2;  //  8.4 MB
  bf16_t* h   = (bf16_t*)(ws + off);                            // 134.2 MB

  cvt_bf16_kernel<<<(M * D / 4 + 255) / 256, 256, 0, stream>>>(x, xb, M * D / 4);
  transpose_cvt_kernel<<<dim3(F / 32, D / 32), dim3(32, 8), 0, stream>>>(w1, w1t, D, F);
  transpose_cvt_kernel<<<dim3(D / 32, F / 32), dim3(32, 8), 0, stream>>>(w2, w2t, F, D);

  // GEMM1 + quantize + PWL-GELU + quantize -> h (bf16)
  gemm_tile<true, bf16_t, false><<<dim3(F / 128, M / 128), 256, 0, stream>>>(xb, w1t, b1, h, M, F, D);
  // GEMM2 + quantize -> out (f32), XCD-locality swizzle (grid 8x128)
  gemm_tile<false, float, true><<<dim3(D / 128, M / 128), 256, 0, stream>>>(h, w2t, b2, out, M, D, F);
}

// Round 4
// 431.449 us; speedup vs baseline: 1.0661x; 1.0661x over previous
//
#include <hip/hip_runtime.h>
#include <hip/hip_bf16.h>

typedef __bf16 bf16_t;
typedef __bf16 bf16x8 __attribute__((ext_vector_type(8)));
typedef __bf16 bf16x4 __attribute__((ext_vector_type(4)));
typedef float f32x4 __attribute__((ext_vector_type(4)));

#define QS   256.0f
#define QINV 0.00390625f

__device__ __forceinline__ void async_copy16(const bf16_t* g, bf16_t* l) {
  __builtin_amdgcn_global_load_lds(
      (__attribute__((address_space(1))) void*)g,
      (__attribute__((address_space(3))) void*)l,
      16, 0, 0);
}

// C = quantize-epilogue(A @ Bt^T + bias)
// A:  [M][K] bf16 row-major; Bt: [N][K] bf16 row-major (B transposed)
// 16x16x32 MFMA, wave computes 64x64 as 4x4 tiles of 16x16.
// LDS XOR swizzle: 16B chunk c of row r stored at phys chunk c ^ (r & 7)
// (staged by permuting which GLOBAL chunk each lane fetches; read side
// xors back) -> ds_read_b128 fragment reads are bank-conflict-free.
// GELU PWL table lives in REGISTERS (lane l holds Yt[l] / slope[l]);
// gathered with __shfl (ds_bpermute crossbar, no bank conflicts).
// XSWZ: remap blocks so all 8 N-blocks of one M-row land on one XCD
// (requires gridDim.x == 8, gridDim.y == 128).
template <bool GELU, typename OutT, bool XSWZ>
__global__ __launch_bounds__(256, 4)
void gemm_tile(const bf16_t* __restrict__ A, const bf16_t* __restrict__ Bt,
               const float* __restrict__ bias, OutT* __restrict__ C,
               int M, int N, int K) {
  __shared__ __attribute__((aligned(16))) bf16_t As[128 * 64];
  __shared__ __attribute__((aligned(16))) bf16_t Bs[128 * 64];

  const int tid = threadIdx.x;
  const int lane = tid & 63;
  const int wv = tid >> 6;
  const int wy = wv >> 1;   // wave row (0/1) -> 64 rows
  const int wx = wv & 1;    // wave col (0/1) -> 64 cols
  const int l15 = lane & 15;
  const int lq = lane >> 4; // quad 0..3

  // register-resident PWL table: lane l holds y(x_l) and slope to x_{l+1}
  float ytA = 0.f, ytS = 0.f;
  if (GELU) {
    float xv = -4.0f + 0.25f * (float)lane;
    float y0 = 0.5f * xv * (1.0f + erff(xv * 0.70710678f));
    float xv1 = xv + 0.25f;
    float y1 = 0.5f * xv1 * (1.0f + erff(xv1 * 0.70710678f));
    ytA = y0;
    ytS = y1 - y0;
  }

  int bx = blockIdx.x, by = blockIdx.y;
  if (XSWZ) {
    // flat dispatch id, x fastest; XCD = flat & 7 on 8-XCD MI355X.
    const int f = by * 8 + bx;
    const int xcd = f & 7;
    const int s = f >> 3;
    bx = s & 7;
    by = xcd * 16 + (s >> 3);  // XCD k owns M-rows [16k, 16k+16)
  }

  const int mBase = by * 128;
  const int nBase = bx * 128;

  const bf16_t* aTile = A + (size_t)mBase * K;
  const bf16_t* bTile = Bt + (size_t)nBase * K;

  f32x4 acc[4][4];
#pragma unroll
  for (int i = 0; i < 4; ++i)
#pragma unroll
    for (int j = 0; j < 4; ++j)
      acc[i][j] = (f32x4){0.f, 0.f, 0.f, 0.f};

  const int srow = tid >> 3;                              // 0..31 (row within 32-row pass)
  const int scb = (((tid & 7) ^ ((tid >> 3) & 7)) * 8);   // swizzled global chunk for this lane

  // read-side swizzle: physical chunk = (ks*4 + lq) ^ (l15 & 7)
  const int swz_r = l15 & 7;

  for (int k0 = 0; k0 < K; k0 += 64) {
    // ---- stage A,B tiles (128 x 64 bf16 each) via async global->LDS, 16B/lane
#pragma unroll
    for (int p = 0; p < 4; ++p) {
      const int row = p * 32 + srow;
      const size_t go = (size_t)row * K + k0 + scb;
      const int lo = (p * 256 + wv * 64) * 8;  // wave-uniform segment base (elements)
      async_copy16(aTile + go, As + lo);
      async_copy16(bTile + go, Bs + lo);
    }
    __syncthreads();  // drains vmcnt: tiles resident

    // ---- compute: 2 k-substeps of 32, 16 MFMA each per wave
#pragma unroll
    for (int ks = 0; ks < 2; ++ks) {
      const int swzA = ((ks * 4 + lq) ^ swz_r) * 8;  // physical chunk offset (elements)
      bf16x8 af[4], bfr[4];
#pragma unroll
      for (int i = 0; i < 4; ++i) {
        af[i]  = *(const bf16x8*)(As + (wy * 64 + i * 16 + l15) * 64 + swzA);
        bfr[i] = *(const bf16x8*)(Bs + (wx * 64 + i * 16 + l15) * 64 + swzA);
      }
#pragma unroll
      for (int i = 0; i < 4; ++i)
#pragma unroll
        for (int j = 0; j < 4; ++j)
          acc[i][j] = __builtin_amdgcn_mfma_f32_16x16x32_bf16(af[i], bfr[j], acc[i][j], 0, 0, 0);
    }
    __syncthreads();  // all waves done reading before next stage
  }

  // ---- epilogue: bias + quantize (+ PWL GELU via register-table shuffle)
  float bj[4];
#pragma unroll
  for (int j = 0; j < 4; ++j)
    bj[j] = bias[nBase + wx * 64 + j * 16 + l15];

#pragma unroll
  for (int i = 0; i < 4; ++i) {
    const int rb = mBase + wy * 64 + i * 16 + lq * 4;
#pragma unroll
    for (int j = 0; j < 4; ++j) {
      const int cn = nBase + wx * 64 + j * 16 + l15;
#pragma unroll
      for (int r = 0; r < 4; ++r) {
        float c = acc[i][j][r] + bj[j];
        float v;
        if (GELU) {
          float xq = rintf(c * QS) * QINV;           // float2fix (Positional_0)
          float t = (xq + 4.0f) * 4.0f;              // exact: /0.25
          int ii = (int)t;
          ii = ii < 0 ? 0 : (ii > 31 ? 31 : ii);
          float f = t - (float)ii;
          float y0 = __shfl(ytA, ii);
          float sl = __shfl(ytS, ii);
          v = fmaf(f, sl, y0);
          v = (xq > 4.0f) ? xq : v;
          v = (xq < -4.0f) ? 0.0f : v;
          v = rintf(v * QS) * QINV;                  // quantize out (+Positional_1 idempotent)
        } else {
          v = rintf(c * QS) * QINV;                  // Positional_2
        }
        C[(size_t)(rb + r) * N + cn] = (OutT)v;
      }
    }
  }
}

__global__ void cvt_bf16_kernel(const float* __restrict__ in, bf16_t* __restrict__ out, int n4) {
  int idx = blockIdx.x * blockDim.x + threadIdx.x;
  if (idx < n4) {
    const float4 v = ((const float4*)in)[idx];
    bf16x4 o;
    o[0] = (bf16_t)v.x; o[1] = (bf16_t)v.y; o[2] = (bf16_t)v.z; o[3] = (bf16_t)v.w;
    ((bf16x4*)out)[idx] = o;
  }
}

// in: [R][C] f32 row-major -> out: [C][R] bf16 row-major
__global__ void transpose_cvt_kernel(const float* __restrict__ in, bf16_t* __restrict__ out,
                                     int R, int C) {
  __shared__ float t[32][33];
  const int c0 = blockIdx.x * 32;
  const int r0 = blockIdx.y * 32;
  const int tx = threadIdx.x;
  const int ty = threadIdx.y;  // 0..7
#pragma unroll
  for (int dy = 0; dy < 32; dy += 8)
    t[ty + dy][tx] = in[(size_t)(r0 + ty + dy) * C + c0 + tx];
  __syncthreads();
#pragma unroll
  for (int dy = 0; dy < 32; dy += 8)
    out[(size_t)(c0 + ty + dy) * R + r0 + tx] = (bf16_t)t[tx][ty + dy];
}

extern "C" void kernel_launch(void* const* d_in, const int* in_sizes, int n_in,
                              void* d_out, int out_size, void* d_ws, size_t ws_size,
                              hipStream_t stream) {
  const float* x  = (const float*)d_in[0];   // [32,512,1024] = [16384][1024]
  const float* w1 = (const float*)d_in[1];   // [1024][4096]
  const float* b1 = (const float*)d_in[2];   // [4096]
  const float* w2 = (const float*)d_in[3];   // [4096][1024]
  const float* b2 = (const float*)d_in[4];   // [1024]
  float* out = (float*)d_out;                // [16384][1024]

  const int M = 16384, D = 1024, F = 4096;

  char* ws = (char*)d_ws;
  size_t off = 0;
  bf16_t* xb  = (bf16_t*)(ws + off); off += (size_t)M * D * 2;  // 33.5 MB
  bf16_t* w1t = (bf16_t*)(ws + off); off += (size_t)D * F * 2;  //  8.4 MB
  bf16_t* w2t = (bf16_t*)(ws + off); off += (size_t)F * D * 2;  //  8.4 MB
  bf16_t* h   = (bf16_t*)(ws + off);                            // 134.2 MB

  cvt_bf16_kernel<<<(M * D / 4 + 255) / 256, 256, 0, stream>>>(x, xb, M * D / 4);
  transpose_cvt_kernel<<<dim3(F / 32, D / 32), dim3(32, 8), 0, stream>>>(w1, w1t, D, F);
  transpose_cvt_kernel<<<dim3(D / 32, F / 32), dim3(32, 8), 0, stream>>>(w2, w2t, F, D);

  // GEMM1 + quantize + PWL-GELU + quantize -> h (bf16)
  gemm_tile<true, bf16_t, false><<<dim3(F / 128, M / 128), 256, 0, stream>>>(xb, w1t, b1, h, M, F, D);
  // GEMM2 + quantize -> out (f32), XCD-locality swizzle (grid 8x128)
  gemm_tile<false, float, true><<<dim3(D / 128, M / 128), 256, 0, stream>>>(h, w2t, b2, out, M, D, F);
}